// Round 2
// 720.447 us; speedup vs baseline: 1.3513x; 1.3513x over previous
//
#include <hip/hip_runtime.h>
#include <hip/hip_bf16.h>

// JointNetwork: out[b,t,u,v] = sum_h tanh(E[bt,h]+D[bu,h]) * W_joint[v,h] + b_joint[v]
// E = enc_out @ W_enc^T + b_enc ; D = dec_out @ W_dec^T + b_dec
// B=4 T=256 U=128 H=512 V=1024.
// R2 == R1 resubmitted (bench infra failed twice; no signal received).
// R1: joint_kernel restructured: 512 threads (8 waves, 2/SIMD), NO W LDS tile,
// B-fragments read directly from L2-resident Wjb with register double-buffer,
// ZERO barriers in the K-loop (Jlds read-only after build). Theory: old kernel
// was latency-bound (1 wave/SIMD + 2 barriers per 32-K step), 11% MfmaUtil.
// Workspace layout (needs 6 MB of d_ws):
//   [0,1MB)   WencT fp32 [512][512]  (W_enc transposed)
//   [1,2MB)   WdecT fp32 [512][512]
//   [2,3MB)   Wjb   bf16 [1024][512] (W_joint converted)
//   [3,5MB)   E     fp32 [1024][512]
//   [5,6MB)   D     fp32 [512][512]

typedef float floatx4 __attribute__((ext_vector_type(4)));
typedef __bf16 bf16x8 __attribute__((ext_vector_type(8)));
typedef unsigned short ushort8v __attribute__((ext_vector_type(8)));

__device__ __forceinline__ unsigned short f2bf(float f) {
  // RNE float->bf16 (inputs are finite, no NaN handling needed)
  unsigned int u = __builtin_bit_cast(unsigned int, f);
  u += 0x7fffu + ((u >> 16) & 1u);
  return (unsigned short)(u >> 16);
}

__device__ __forceinline__ float fast_tanh(float x) {
  // tanh(x) = 1 - 2/(exp(2x)+1); exp->inf => 1, exp->0 => -1 (branch-free)
  float z = __expf(2.0f * x);
  return 1.0f - __fdividef(2.0f, z + 1.0f);
}

// ---------------------------------------------------------------- prep ------
// grid 1024 x 256: blocks [0,256) transpose W_enc, [256,512) transpose W_dec,
// [512,1024) convert W_joint fp32 -> bf16.
__global__ void prep_kernel(const float* __restrict__ W_enc,
                            const float* __restrict__ W_dec,
                            const float* __restrict__ W_joint,
                            float* __restrict__ WencT, float* __restrict__ WdecT,
                            unsigned short* __restrict__ Wjb) {
  __shared__ float tile[32][33];
  const int bid = blockIdx.x, t = threadIdx.x;
  if (bid < 512) {
    const float* src = (bid < 256) ? W_enc : W_dec;
    float* dst = (bid < 256) ? WencT : WdecT;
    const int tb = bid & 255;
    const int tr = (tb >> 4) * 32, tc = (tb & 15) * 32;
    const int tx = t & 31, ty = t >> 5;
#pragma unroll
    for (int i = 0; i < 4; ++i) {
      int r = ty + i * 8;
      tile[r][tx] = src[(tr + r) * 512 + tc + tx];
    }
    __syncthreads();
#pragma unroll
    for (int i = 0; i < 4; ++i) {
      int r = ty + i * 8;
      dst[(tc + r) * 512 + tr + tx] = tile[tx][r];
    }
  } else {
    const int cid = bid - 512;
    const int base = (cid * 256 + t) * 4;
    float4 v = *(const float4*)&W_joint[base];
    ushort4 o;
    o.x = f2bf(v.x); o.y = f2bf(v.y); o.z = f2bf(v.z); o.w = f2bf(v.w);
    *(ushort4*)&Wjb[base] = o;
  }
}

// ---------------------------------------------------------------- proj ------
// grid 192 x 256: blocks [0,128) compute E rows (8/block), [128,192) D rows.
// out[m][n] = sum_k X[m][k] * Wt[k][n] + bias[n]   (Wt = W^T, coalesced over n)
__global__ void proj_kernel(const float* __restrict__ enc,
                            const float* __restrict__ dec,
                            const float* __restrict__ WencT,
                            const float* __restrict__ WdecT,
                            const float* __restrict__ b_enc,
                            const float* __restrict__ b_dec,
                            float* __restrict__ E, float* __restrict__ D) {
  __shared__ float Xs[8 * 512];
  const int bid = blockIdx.x, t = threadIdx.x;
  const float *X, *Wt, *bias;
  float* out;
  int m0;
  if (bid < 128) { X = enc; Wt = WencT; bias = b_enc; out = E; m0 = bid * 8; }
  else { X = dec; Wt = WdecT; bias = b_dec; out = D; m0 = (bid - 128) * 8; }

#pragma unroll
  for (int i = 0; i < 4; ++i) {
    int f = (i * 256 + t) * 4;
    *(float4*)&Xs[f] = *(const float4*)&X[m0 * 512 + f];
  }
  __syncthreads();

  const int tn = t & 127, tm = t >> 7;  // n = 4*tn, rows m0 + tm*4 + i
  float acc[4][4];
#pragma unroll
  for (int i = 0; i < 4; ++i)
#pragma unroll
    for (int j = 0; j < 4; ++j) acc[i][j] = 0.f;

  for (int k0 = 0; k0 < 512; k0 += 4) {
    float4 xv[4];
#pragma unroll
    for (int i = 0; i < 4; ++i)
      xv[i] = *(const float4*)&Xs[(tm * 4 + i) * 512 + k0];
#pragma unroll
    for (int kk = 0; kk < 4; ++kk) {
      float4 wv = *(const float4*)&Wt[(k0 + kk) * 512 + tn * 4];
#pragma unroll
      for (int i = 0; i < 4; ++i) {
        float x = ((const float*)&xv[i])[kk];
        acc[i][0] += x * wv.x;
        acc[i][1] += x * wv.y;
        acc[i][2] += x * wv.z;
        acc[i][3] += x * wv.w;
      }
    }
  }
  float4 bv = *(const float4*)&bias[tn * 4];
#pragma unroll
  for (int i = 0; i < 4; ++i) {
    float4 o;
    o.x = acc[i][0] + bv.x; o.y = acc[i][1] + bv.y;
    o.z = acc[i][2] + bv.z; o.w = acc[i][3] + bv.w;
    *(float4*)&out[(m0 + tm * 4 + i) * 512 + tn * 4] = o;
  }
}

// ---------------------------------------------------------------- main ------
// One block per (b,t), 512 threads = 8 waves (2/SIMD). J-panel tanh(E+D) as
// bf16 [128][520] in LDS (133 KB, built once, ONE barrier total). Each wave
// owns 64 n-cols; ni in {0,1} covers 1024 cols. B-fragments come straight
// from global Wjb (1 MB, L2-resident; each element consumed by exactly one
// wave once per block -> LDS staging had zero reuse). B is register
// double-buffered via a manual 2-step unroll; NO __syncthreads in the K-loop.
__global__ __launch_bounds__(512, 2) void joint_kernel(
    const float* __restrict__ E, const float* __restrict__ D,
    const unsigned short* __restrict__ Wjb, const float* __restrict__ b_joint,
    float* __restrict__ out) {
  __shared__ __align__(16) unsigned short Jlds[128 * 520];  // 133 KB, pad 512->520

  const int t = threadIdx.x;          // 0..511
  const int bt = blockIdx.x;          // b*256 + t_idx
  const int b = bt >> 8;
  const int lane = t & 63;
  const int w = t >> 6;               // wave id 0..7: n-range ni*512 + w*64
  const int quad = lane >> 4;
  const int ln15 = lane & 15;

  const float* Dbase = D + (size_t)(b * 128) * 512;
  const float* Erow = E + (size_t)bt * 512;

  // ---- build J panel: 8192 chunks of 8 h-elements; wave-linear LDS writes
#pragma unroll 4
  for (int it = 0; it < 16; ++it) {
    int idx = it * 512 + t;
    int u = idx >> 6, c = idx & 63;
    const float* dp = Dbase + u * 512 + c * 8;
    float4 d0 = *(const float4*)dp;
    float4 d1 = *(const float4*)(dp + 4);
    float4 e0 = *(const float4*)(Erow + c * 8);
    float4 e1 = *(const float4*)(Erow + c * 8 + 4);
    ushort8v v;
    v[0] = f2bf(fast_tanh(e0.x + d0.x));
    v[1] = f2bf(fast_tanh(e0.y + d0.y));
    v[2] = f2bf(fast_tanh(e0.z + d0.z));
    v[3] = f2bf(fast_tanh(e0.w + d0.w));
    v[4] = f2bf(fast_tanh(e1.x + d1.x));
    v[5] = f2bf(fast_tanh(e1.y + d1.y));
    v[6] = f2bf(fast_tanh(e1.z + d1.z));
    v[7] = f2bf(fast_tanh(e1.w + d1.w));
    *(ushort8v*)&Jlds[u * 520 + c * 8] = v;
  }

  // per-wave B base: element (ni,nf,k) at wbase + ni*512*512 + nf*16*512 + k
  const unsigned short* wbase = Wjb + (size_t)(w * 64 + ln15) * 512 + quad * 8;

  // prefetch B frags for (ni=0, k0=0) while the barrier settles
  bf16x8 bcur[4], bnxt[4];
#pragma unroll
  for (int nf = 0; nf < 4; ++nf)
    bcur[nf] = *(const bf16x8*)(wbase + nf * (16 * 512));

  __syncthreads();  // Jlds ready; the ONLY barrier in this kernel

#pragma unroll 1
  for (int ni = 0; ni < 2; ++ni) {
    floatx4 acc[8][4];
#pragma unroll
    for (int mf = 0; mf < 8; ++mf)
#pragma unroll
      for (int nf = 0; nf < 4; ++nf)
        acc[mf][nf] = (floatx4){0.f, 0.f, 0.f, 0.f};
    float bj[4];
#pragma unroll
    for (int nf = 0; nf < 4; ++nf)
      bj[nf] = b_joint[ni * 512 + w * 64 + nf * 16 + ln15];

#pragma unroll 1
    for (int kp = 0; kp < 8; ++kp) {
      // ---- step A: ks = 2*kp, consumes bcur, prefetches bnxt (ks=2kp+1)
      {
        const int k0 = kp * 64;
        const unsigned short* wb = wbase + ni * (512 * 512) + (k0 + 32);
#pragma unroll
        for (int nf = 0; nf < 4; ++nf)
          bnxt[nf] = *(const bf16x8*)(wb + nf * (16 * 512));
        bf16x8 af[8];
#pragma unroll
        for (int mf = 0; mf < 8; ++mf)
          af[mf] = *(const bf16x8*)&Jlds[(mf * 16 + ln15) * 520 + k0 + quad * 8];
#pragma unroll
        for (int mf = 0; mf < 8; ++mf)
#pragma unroll
          for (int nf = 0; nf < 4; ++nf)
            acc[mf][nf] = __builtin_amdgcn_mfma_f32_16x16x32_bf16(
                af[mf], bcur[nf], acc[mf][nf], 0, 0, 0);
      }
      // ---- step B: ks = 2*kp+1, consumes bnxt, prefetches bcur (ks=2kp+2,
      //      wrapping into next ni's k=0 at the tile edge)
      {
        const int k0 = kp * 64 + 32;
        int nk = k0 + 32, nni = ni;
        if (nk == 512) { nk = 0; nni = ni ^ 1; }  // ni=1 edge reloads ni=0 (unused, harmless)
        const unsigned short* wb = wbase + nni * (512 * 512) + nk;
#pragma unroll
        for (int nf = 0; nf < 4; ++nf)
          bcur[nf] = *(const bf16x8*)(wb + nf * (16 * 512));
        bf16x8 af[8];
#pragma unroll
        for (int mf = 0; mf < 8; ++mf)
          af[mf] = *(const bf16x8*)&Jlds[(mf * 16 + ln15) * 520 + k0 + quad * 8];
#pragma unroll
        for (int mf = 0; mf < 8; ++mf)
#pragma unroll
          for (int nf = 0; nf < 4; ++nf)
            acc[mf][nf] = __builtin_amdgcn_mfma_f32_16x16x32_bf16(
                af[mf], bnxt[nf], acc[mf][nf], 0, 0, 0);
      }
    }

    // epilogue: D[row=quad*4+r][col=ln15] per frag; add bias; scalar stores
    float* obase = out + (size_t)bt * (128 * 1024) + ni * 512 + w * 64;
#pragma unroll
    for (int mf = 0; mf < 8; ++mf) {
#pragma unroll
      for (int r = 0; r < 4; ++r) {
        int m = mf * 16 + quad * 4 + r;
        float* orow = obase + (size_t)m * 1024;
#pragma unroll
        for (int nf = 0; nf < 4; ++nf)
          orow[nf * 16 + ln15] = acc[mf][nf][r] + bj[nf];
      }
    }
  }
}

extern "C" void kernel_launch(void* const* d_in, const int* in_sizes, int n_in,
                              void* d_out, int out_size, void* d_ws, size_t ws_size,
                              hipStream_t stream) {
  const float* enc_out = (const float*)d_in[0];
  const float* dec_out = (const float*)d_in[1];
  const float* W_enc   = (const float*)d_in[2];
  const float* b_enc   = (const float*)d_in[3];
  const float* W_dec   = (const float*)d_in[4];
  const float* b_dec   = (const float*)d_in[5];
  const float* W_joint = (const float*)d_in[6];
  const float* b_joint = (const float*)d_in[7];
  float* out = (float*)d_out;

  char* ws = (char*)d_ws;  // needs 6 MB
  float* WencT = (float*)(ws);
  float* WdecT = (float*)(ws + (1u << 20));
  unsigned short* Wjb = (unsigned short*)(ws + (2u << 20));
  float* E = (float*)(ws + (3u << 20));
  float* Dm = (float*)(ws + (5u << 20));

  prep_kernel<<<1024, 256, 0, stream>>>(W_enc, W_dec, W_joint, WencT, WdecT, Wjb);
  proj_kernel<<<192, 256, 0, stream>>>(enc_out, dec_out, WencT, WdecT, b_enc, b_dec, E, Dm);
  joint_kernel<<<1024, 512, 0, stream>>>(E, Dm, Wjb, b_joint, out);
}